// Round 1
// baseline (81.421 us; speedup 1.0000x reference)
//
#include <hip/hip_runtime.h>

constexpr int EMB    = 300;
constexpr int HIDDEN = 512;
constexpr int SEQ    = 512;
constexpr int BATCH  = 1024;
constexpr int GB     = 8;    // batch rows per block in MLP kernel

// ---------------- Kernel A: embedding gather + masked mean pool ----------------
// One block per batch element. 320 threads = 5 waves; lanes 0..299 own one
// embedding dim each. Tokens staged in LDS first, then a gather-accumulate
// loop with 4 independent accumulators for load ILP.
__global__ __launch_bounds__(320) void pool_kernel(
    const int* __restrict__ text,      // [SEQ, BATCH]
    const int* __restrict__ lengths,   // [BATCH]
    const float* __restrict__ emb,     // [VOCAB, EMB]
    float* __restrict__ pooled)        // [BATCH, EMB]
{
    const int b   = blockIdx.x;
    const int len = lengths[b];

    __shared__ int toks[SEQ];
    for (int s = threadIdx.x; s < len; s += 320) {
        toks[s] = text[s * BATCH + b];
    }
    __syncthreads();

    const int e = threadIdx.x;
    if (e < EMB) {
        float a0 = 0.f, a1 = 0.f, a2 = 0.f, a3 = 0.f;
        int s = 0;
        for (; s + 4 <= len; s += 4) {
            a0 += emb[(size_t)toks[s + 0] * EMB + e];
            a1 += emb[(size_t)toks[s + 1] * EMB + e];
            a2 += emb[(size_t)toks[s + 2] * EMB + e];
            a3 += emb[(size_t)toks[s + 3] * EMB + e];
        }
        for (; s < len; ++s) {
            a0 += emb[(size_t)toks[s] * EMB + e];
        }
        const float acc = (a0 + a1) + (a2 + a3);
        pooled[b * EMB + e] = acc / (float)len;
    }
}

// ---------------- Kernel B: fused fc1 + relu + fc2 ----------------
// 8 batch rows per block so W1 (614 KB) is swept only BATCH/GB = 128 times
// (L2-resident). pooled rows staged transposed pT[e][g] so the fc1 inner loop
// is: 1 coalesced W1 load + 2 uniform ds_read_b128 + 8 FMA.
__global__ __launch_bounds__(512) void mlp_kernel(
    const float* __restrict__ pooled,  // [BATCH, EMB]
    const float* __restrict__ W1,      // [EMB, HIDDEN]
    const float* __restrict__ b1,      // [HIDDEN]
    const float* __restrict__ W2,      // [HIDDEN, 2]
    const float* __restrict__ b2,      // [2]
    float* __restrict__ out)           // [BATCH, 2]
{
    __shared__ float pT[EMB][GB];          // 9.4 KB
    __shared__ float h[GB][HIDDEN];        // 16 KB

    const int b0  = blockIdx.x * GB;
    const int tid = threadIdx.x;

    // stage pooled rows, transposed
    for (int i = tid; i < EMB * GB; i += 512) {
        const int e = i >> 3;
        const int g = i & (GB - 1);
        pT[e][g] = pooled[(b0 + g) * EMB + e];
    }
    __syncthreads();

    // fc1 + relu: thread j computes h[g][j] for all g
    const int j = tid;                     // HIDDEN == 512 == blockDim
    float acc[GB];
    const float bias1 = b1[j];
#pragma unroll
    for (int g = 0; g < GB; ++g) acc[g] = bias1;

    for (int e = 0; e < EMB; ++e) {
        const float w = W1[e * HIDDEN + j];
        const float4* pv = reinterpret_cast<const float4*>(&pT[e][0]);
        const float4 pa = pv[0];
        const float4 pb = pv[1];
        acc[0] += pa.x * w;
        acc[1] += pa.y * w;
        acc[2] += pa.z * w;
        acc[3] += pa.w * w;
        acc[4] += pb.x * w;
        acc[5] += pb.y * w;
        acc[6] += pb.z * w;
        acc[7] += pb.w * w;
    }
#pragma unroll
    for (int g = 0; g < GB; ++g) h[g][j] = fmaxf(acc[g], 0.f);
    __syncthreads();

    // fc2: wave w (64 lanes) reduces batch row g == w
    const int wave = tid >> 6;
    const int lane = tid & 63;
    float s0 = 0.f, s1 = 0.f;
    for (int jj = lane; jj < HIDDEN; jj += 64) {
        const float hv = h[wave][jj];
        s0 += hv * W2[jj * 2 + 0];
        s1 += hv * W2[jj * 2 + 1];
    }
#pragma unroll
    for (int off = 32; off > 0; off >>= 1) {
        s0 += __shfl_down(s0, off);
        s1 += __shfl_down(s1, off);
    }
    if (lane == 0) {
        out[(b0 + wave) * 2 + 0] = s0 + b2[0];
        out[(b0 + wave) * 2 + 1] = s1 + b2[1];
    }
}

extern "C" void kernel_launch(void* const* d_in, const int* in_sizes, int n_in,
                              void* d_out, int out_size, void* d_ws, size_t ws_size,
                              hipStream_t stream) {
    const int*   text    = (const int*)d_in[0];
    const int*   lengths = (const int*)d_in[1];
    const float* emb     = (const float*)d_in[2];
    const float* W1      = (const float*)d_in[3];
    const float* b1      = (const float*)d_in[4];
    const float* W2      = (const float*)d_in[5];
    const float* b2      = (const float*)d_in[6];
    float*       out     = (float*)d_out;
    float*       pooled  = (float*)d_ws;   // BATCH*EMB floats = 1.2 MB

    pool_kernel<<<BATCH, 320, 0, stream>>>(text, lengths, emb, pooled);
    mlp_kernel<<<BATCH / GB, 512, 0, stream>>>(pooled, W1, b1, W2, b2, out);
}

// Round 2
// 73.531 us; speedup vs baseline: 1.1073x; 1.1073x over previous
//
#include <hip/hip_runtime.h>

constexpr int EMB    = 300;
constexpr int EMB4   = 75;    // EMB / 4 (float4 chunks per row)
constexpr int HIDDEN = 512;
constexpr int SEQ    = 512;
constexpr int BATCH  = 1024;
constexpr int GB     = 4;     // batch rows per block in MLP kernel
constexpr int NSG    = 4;     // seq sub-groups inside a pool block

__device__ __forceinline__ float4 f4add(float4 a, float4 b) {
    return make_float4(a.x + b.x, a.y + b.y, a.z + b.z, a.w + b.w);
}

// ---------------- Kernel A: embedding gather + masked mean pool (partial) ----
// Grid (BATCH, NS). Block (b, h) handles s in [h*chunk, min(len,(h+1)*chunk)).
// 320 threads: lanes 0..299 = 4 seq-groups x 75 float4-lanes. Each thread
// gathers 16 B per row with a 4-deep unroll (4 independent float4 chains).
// Writes UNSCALED partial sums to part[h][b][EMB] (zeros if range empty).
__global__ __launch_bounds__(320) void pool_kernel(
    const int* __restrict__ text,      // [SEQ, BATCH]
    const int* __restrict__ lengths,   // [BATCH]
    const float* __restrict__ emb,     // [VOCAB, EMB]
    float* __restrict__ part,          // [NS, BATCH, EMB]
    int NS)
{
    const int b   = blockIdx.x;
    const int h   = blockIdx.y;
    const int len = lengths[b];
    const int chunk = (len + NS - 1) / NS;
    const int s0  = h * chunk;
    const int s1  = min(len, s0 + chunk);
    const int n   = max(0, s1 - s0);

    __shared__ int    toks[SEQ];
    __shared__ float4 red[NSG][EMB4];

    for (int t = threadIdx.x; t < n; t += 320)
        toks[t] = text[(s0 + t) * BATCH + b];
    __syncthreads();

    const int t = threadIdx.x;
    if (t < NSG * EMB4) {
        const int g = t / EMB4;   // seq group 0..3
        const int c = t % EMB4;   // float4 chunk 0..74
        float4 a0 = make_float4(0.f, 0.f, 0.f, 0.f);
        float4 a1 = a0, a2 = a0, a3 = a0;
        int i = g;
        for (; i + 12 < n; i += 16) {
            const float4* r0 = (const float4*)(emb + (size_t)toks[i +  0] * EMB);
            const float4* r1 = (const float4*)(emb + (size_t)toks[i +  4] * EMB);
            const float4* r2 = (const float4*)(emb + (size_t)toks[i +  8] * EMB);
            const float4* r3 = (const float4*)(emb + (size_t)toks[i + 12] * EMB);
            a0 = f4add(a0, r0[c]);
            a1 = f4add(a1, r1[c]);
            a2 = f4add(a2, r2[c]);
            a3 = f4add(a3, r3[c]);
        }
        for (; i < n; i += 4) {
            const float4* r = (const float4*)(emb + (size_t)toks[i] * EMB);
            a0 = f4add(a0, r[c]);
        }
        red[g][c] = f4add(f4add(a0, a1), f4add(a2, a3));
    }
    __syncthreads();

    if (t < EMB4) {
        const float4 s = f4add(f4add(red[0][t], red[1][t]),
                               f4add(red[2][t], red[3][t]));
        float4* dst = (float4*)(part + ((size_t)h * BATCH + b) * EMB);
        dst[t] = s;   // unconditional: zeros for empty ranges (ws is poisoned)
    }
}

// ---------------- Kernel B: combine partials + fc1 + relu + fc2 ----------------
// GB=4 batch rows/block -> 256 blocks (1 per CU). Staging sums the NS partials
// and divides by len. fc1 inner loop unrolled x4: 4 coalesced W1 loads +
// 4 uniform ds_read_b128 + 16 FMA per step.
__global__ __launch_bounds__(512) void mlp_kernel(
    const float* __restrict__ part,    // [NS, BATCH, EMB]
    const int* __restrict__ lengths,   // [BATCH]
    const float* __restrict__ W1,      // [EMB, HIDDEN]
    const float* __restrict__ b1,      // [HIDDEN]
    const float* __restrict__ W2,      // [HIDDEN, 2]
    const float* __restrict__ b2,      // [2]
    float* __restrict__ out,           // [BATCH, 2]
    int NS)
{
    __shared__ float pT[EMB][GB];        // 4.8 KB
    __shared__ float h[GB][HIDDEN];      // 8 KB

    const int b0  = blockIdx.x * GB;
    const int tid = threadIdx.x;

    // stage: combine NS partials, scale by 1/len, store transposed
    for (int i = tid; i < EMB * GB; i += 512) {
        const int g = i / EMB;
        const int e = i - g * EMB;
        float s = 0.f;
        for (int ns = 0; ns < NS; ++ns)
            s += part[((size_t)ns * BATCH + b0 + g) * EMB + e];
        pT[e][g] = s / (float)lengths[b0 + g];
    }
    __syncthreads();

    // fc1 + relu: thread j computes h[g][j] for g=0..3
    const int j = tid;                   // HIDDEN == blockDim
    const float bias1 = b1[j];
    float4 acc = make_float4(bias1, bias1, bias1, bias1);
    for (int e = 0; e < EMB; e += 4) {   // EMB = 300 = 4*75, exact
        const float w0 = W1[(e + 0) * HIDDEN + j];
        const float w1 = W1[(e + 1) * HIDDEN + j];
        const float w2 = W1[(e + 2) * HIDDEN + j];
        const float w3 = W1[(e + 3) * HIDDEN + j];
        const float4 p0 = *(const float4*)&pT[e + 0][0];
        const float4 p1 = *(const float4*)&pT[e + 1][0];
        const float4 p2 = *(const float4*)&pT[e + 2][0];
        const float4 p3 = *(const float4*)&pT[e + 3][0];
        acc.x += p0.x * w0 + p1.x * w1 + p2.x * w2 + p3.x * w3;
        acc.y += p0.y * w0 + p1.y * w1 + p2.y * w2 + p3.y * w3;
        acc.z += p0.z * w0 + p1.z * w1 + p2.z * w2 + p3.z * w3;
        acc.w += p0.w * w0 + p1.w * w1 + p2.w * w2 + p3.w * w3;
    }
    h[0][j] = fmaxf(acc.x, 0.f);
    h[1][j] = fmaxf(acc.y, 0.f);
    h[2][j] = fmaxf(acc.z, 0.f);
    h[3][j] = fmaxf(acc.w, 0.f);
    __syncthreads();

    // fc2: wave g (g < GB) reduces batch row b0+g
    const int wave = tid >> 6;
    const int lane = tid & 63;
    if (wave < GB) {
        float s0 = 0.f, s1 = 0.f;
        for (int jj = lane; jj < HIDDEN; jj += 64) {
            const float  hv = h[wave][jj];
            const float2 w  = *(const float2*)&W2[jj * 2];
            s0 += hv * w.x;
            s1 += hv * w.y;
        }
#pragma unroll
        for (int off = 32; off > 0; off >>= 1) {
            s0 += __shfl_down(s0, off);
            s1 += __shfl_down(s1, off);
        }
        if (lane == 0) {
            out[(b0 + wave) * 2 + 0] = s0 + b2[0];
            out[(b0 + wave) * 2 + 1] = s1 + b2[1];
        }
    }
}

extern "C" void kernel_launch(void* const* d_in, const int* in_sizes, int n_in,
                              void* d_out, int out_size, void* d_ws, size_t ws_size,
                              hipStream_t stream) {
    const int*   text    = (const int*)d_in[0];
    const int*   lengths = (const int*)d_in[1];
    const float* emb     = (const float*)d_in[2];
    const float* W1      = (const float*)d_in[3];
    const float* b1      = (const float*)d_in[4];
    const float* W2      = (const float*)d_in[5];
    const float* b2      = (const float*)d_in[6];
    float*       out     = (float*)d_out;
    float*       part    = (float*)d_ws;

    const size_t poolBytes = (size_t)BATCH * EMB * sizeof(float);
    const int NS = (ws_size >= 4 * poolBytes) ? 4
                 : (ws_size >= 2 * poolBytes) ? 2 : 1;

    pool_kernel<<<dim3(BATCH, NS), 320, 0, stream>>>(text, lengths, emb, part, NS);
    mlp_kernel<<<BATCH / GB, 512, 0, stream>>>(part, lengths, W1, b1, W2, b2, out, NS);
}